// Round 1
// baseline (324.792 us; speedup 1.0000x reference)
//
#include <hip/hip_runtime.h>
#include <hip/hip_bf16.h>

// SelfAttention: B=4, S=2048, EMBED=1024, H=16, D=64
// out = ((softmax((Q Wq^T)(K Wk^T)^T / 32) (V Wv^T)) reshaped) Wo^T + bo
//
// Pipeline (all bf16 MFMA internally, f32 in/out, 2%-of-max tolerance):
//   1) proj_kernel : q/k/v (f32) x Wq/Wk/Wv -> qp/kp/vp bf16 [b][h][s][d]
//   2) wo_cvt      : Wo f32 -> bf16 (same [n][k] layout; it IS the B-frag layout)
//   3) attn_kernel : flash attention per (b,h), QBLK=64, KBLK=64 -> ao bf16 [b*s][e]
//   4) out_gemm    : ao (8192x1024) @ Wo^T + bo -> out f32

#define SS 2048
#define HH 16
#define DD 64

typedef __attribute__((ext_vector_type(8))) short bf16x8;
typedef __attribute__((ext_vector_type(4))) short s16x4;
typedef __attribute__((ext_vector_type(4))) float f32x4;

__device__ __forceinline__ short f2bf(float f) {
  union { float f; unsigned u; } c; c.f = f;
  unsigned r = (c.u + 0x7FFFu + ((c.u >> 16) & 1u)) >> 16;  // RNE
  return (short)r;
}

// ---------------------------------------------------------------- projections
// rows r = (b*S + s)*16 + h are contiguous (64 f32 each). Block = 128 rows.
__global__ __launch_bounds__(256) void proj_kernel(
    const float* __restrict__ xq, const float* __restrict__ xk, const float* __restrict__ xv,
    const float* __restrict__ Wq, const float* __restrict__ Wk, const float* __restrict__ Wv,
    short* __restrict__ qp, short* __restrict__ kp, short* __restrict__ vp)
{
  __shared__ short xlds[128][72];      // +8 pad: 144B stride, 16B aligned
  __shared__ short wlds[3][64][72];
  const int t = threadIdx.x;
  const int lane = t & 63;
  const int w = t >> 6;
  const int l15 = lane & 15, l4 = lane >> 4;

  const float* wsrc[3] = {Wq, Wk, Wv};
#pragma unroll
  for (int z = 0; z < 3; ++z) {
#pragma unroll
    for (int i = 0; i < 4; ++i) {
      int fi = (t + i * 256) * 4;                  // 4096 f32
      int row = fi >> 6, col = fi & 63;
      float4 a = *(const float4*)(wsrc[z] + fi);
      s16x4 sv = { f2bf(a.x), f2bf(a.y), f2bf(a.z), f2bf(a.w) };
      *(s16x4*)&wlds[z][row][col] = sv;
    }
  }

  const long r0 = (long)blockIdx.x * 128;
  const float* xin[3] = {xq, xk, xv};
  short* outp[3] = {qp, kp, vp};

#pragma unroll
  for (int z = 0; z < 3; ++z) {
    __syncthreads();
    const float* src = xin[z] + r0 * 64;
#pragma unroll
    for (int i = 0; i < 8; ++i) {
      int fi = (t + i * 256) * 4;                  // 8192 f32
      int row = fi >> 6, col = fi & 63;
      float4 a = *(const float4*)(src + fi);
      s16x4 sv = { f2bf(a.x), f2bf(a.y), f2bf(a.z), f2bf(a.w) };
      *(s16x4*)&xlds[row][col] = sv;
    }
    __syncthreads();

    bf16x8 af[2][2];
#pragma unroll
    for (int mi = 0; mi < 2; ++mi)
#pragma unroll
      for (int kb = 0; kb < 2; ++kb)
        af[mi][kb] = *(const bf16x8*)&xlds[w * 32 + mi * 16 + l15][kb * 32 + l4 * 8];

    f32x4 acc[2][4];
#pragma unroll
    for (int mi = 0; mi < 2; ++mi)
#pragma unroll
      for (int nt = 0; nt < 4; ++nt)
        acc[mi][nt] = (f32x4){0.f, 0.f, 0.f, 0.f};

#pragma unroll
    for (int nt = 0; nt < 4; ++nt)
#pragma unroll
      for (int kb = 0; kb < 2; ++kb) {
        // B[d][e] = W[e][d]  -> read W rows along d (contiguous)
        bf16x8 bfr = *(const bf16x8*)&wlds[z][nt * 16 + l15][kb * 32 + l4 * 8];
#pragma unroll
        for (int mi = 0; mi < 2; ++mi)
          acc[mi][nt] = __builtin_amdgcn_mfma_f32_16x16x32_bf16(af[mi][kb], bfr, acc[mi][nt], 0, 0, 0);
      }

    short* dst = outp[z];
#pragma unroll
    for (int mi = 0; mi < 2; ++mi)
#pragma unroll
      for (int nt = 0; nt < 4; ++nt)
#pragma unroll
        for (int j = 0; j < 4; ++j) {
          int r = (int)r0 + w * 32 + mi * 16 + l4 * 4 + j;   // (b*S+s)*16+h
          int e = nt * 16 + l15;
          int h = r & 15, bs = r >> 4;
          int b = bs >> 11, s = bs & 2047;
          dst[(((long)(b * 16 + h) * 2048 + s) << 6) + e] = f2bf(acc[mi][nt][j]);
        }
  }
}

// ---------------------------------------------------------------- Wo -> bf16
__global__ __launch_bounds__(256) void wo_cvt(const float* __restrict__ Wo,
                                              short* __restrict__ wob) {
  long i = ((long)blockIdx.x * 256 + threadIdx.x) * 4;
  float4 a = *(const float4*)(Wo + i);
  s16x4 sv = { f2bf(a.x), f2bf(a.y), f2bf(a.z), f2bf(a.w) };
  *(s16x4*)(wob + i) = sv;
}

// ---------------------------------------------------------------- attention
// grid (32 q-tiles, 64 bh). Block = 4 waves, each wave owns 16 q-rows.
__global__ __launch_bounds__(256) void attn_kernel(
    const short* __restrict__ qp, const short* __restrict__ kp, const short* __restrict__ vp,
    const int* __restrict__ mask, short* __restrict__ ao)
{
  __shared__ short klds[64][72];        // K tile row-major [kv][d]
  __shared__ short vtlds[64][72];       // V tile transposed [d][kv]
  __shared__ short plds[4][16][72];     // per-wave P round-trip
  __shared__ int   mlds[2048];
  const int t = threadIdx.x, lane = t & 63, w = t >> 6;
  const int l15 = lane & 15, l4 = lane >> 4;
  const int qt = blockIdx.x, bh = blockIdx.y;
  const int b = bh >> 4, h = bh & 15;
  const short* qb  = qp + (long)bh * SS * DD;
  const short* kbp = kp + (long)bh * SS * DD;
  const short* vbp = vp + (long)bh * SS * DD;

#pragma unroll
  for (int i = 0; i < 8; ++i) mlds[t + i * 256] = mask[b * SS + t + i * 256];

  const int q0 = qt * 64 + w * 16;
  bf16x8 qa[2];
#pragma unroll
  for (int kb = 0; kb < 2; ++kb)
    qa[kb] = *(const bf16x8*)(qb + (long)(q0 + l15) * DD + kb * 32 + l4 * 8);

  f32x4 oacc[4];
#pragma unroll
  for (int nt = 0; nt < 4; ++nt) oacc[nt] = (f32x4){0.f, 0.f, 0.f, 0.f};
  float mrow[4], lrow[4];
#pragma unroll
  for (int j = 0; j < 4; ++j) { mrow[j] = -1e30f; lrow[j] = 0.f; }
  const float SC = 0.03125f * 1.4426950408889634f;   // (1/sqrt(1024)) * log2(e)

  for (int kt = 0; kt < SS / 64; ++kt) {
    const int k0 = kt * 64;
    __syncthreads();
    // stage K row-major (coalesced)
#pragma unroll
    for (int i = 0; i < 2; ++i) {
      int f = t * 8 + i * 2048;
      int row = f >> 6, col = f & 63;
      *(bf16x8*)&klds[row][col] = *(const bf16x8*)(kbp + (long)(k0 + row) * DD + col);
    }
    // stage V transposed: thread t reads row (t&63), d chunk (t>>6)*16
    {
      int kk = t & 63, d0 = (t >> 6) * 16;
      bf16x8 v0 = *(const bf16x8*)(vbp + (long)(k0 + kk) * DD + d0);
      bf16x8 v1 = *(const bf16x8*)(vbp + (long)(k0 + kk) * DD + d0 + 8);
#pragma unroll
      for (int j = 0; j < 8; ++j) vtlds[d0 + j][kk] = v0[j];
#pragma unroll
      for (int j = 0; j < 8; ++j) vtlds[d0 + 8 + j][kk] = v1[j];
    }
    __syncthreads();

    // S = Q K^T  (D layout: row=(l>>4)*4+j, col=nt*16+(l&15))
    f32x4 sacc[4];
#pragma unroll
    for (int nt = 0; nt < 4; ++nt) {
      sacc[nt] = (f32x4){0.f, 0.f, 0.f, 0.f};
#pragma unroll
      for (int kb = 0; kb < 2; ++kb) {
        bf16x8 bfr = *(const bf16x8*)&klds[nt * 16 + l15][kb * 32 + l4 * 8];
        sacc[nt] = __builtin_amdgcn_mfma_f32_16x16x32_bf16(qa[kb], bfr, sacc[nt], 0, 0, 0);
      }
    }
    // scale to log2 domain + mask
#pragma unroll
    for (int nt = 0; nt < 4; ++nt) {
      bool mz = (mlds[k0 + nt * 16 + l15] == 0);
#pragma unroll
      for (int j = 0; j < 4; ++j) {
        float s = sacc[nt][j] * SC;
        sacc[nt][j] = mz ? -1e30f : s;
      }
    }
    // online softmax per q-row j (reduce across the 16 lanes of each l4 group)
#pragma unroll
    for (int j = 0; j < 4; ++j) {
      float mx = fmaxf(fmaxf(sacc[0][j], sacc[1][j]), fmaxf(sacc[2][j], sacc[3][j]));
      mx = fmaxf(mx, __shfl_xor(mx, 1));
      mx = fmaxf(mx, __shfl_xor(mx, 2));
      mx = fmaxf(mx, __shfl_xor(mx, 4));
      mx = fmaxf(mx, __shfl_xor(mx, 8));
      float mnew = fmaxf(mrow[j], mx);
      float al = exp2f(mrow[j] - mnew);
      float sum = 0.f;
#pragma unroll
      for (int nt = 0; nt < 4; ++nt) {
        float p = exp2f(sacc[nt][j] - mnew);
        sacc[nt][j] = p;
        sum += p;
      }
      sum += __shfl_xor(sum, 1);
      sum += __shfl_xor(sum, 2);
      sum += __shfl_xor(sum, 4);
      sum += __shfl_xor(sum, 8);
      lrow[j] = lrow[j] * al + sum;
      mrow[j] = mnew;
#pragma unroll
      for (int nt = 0; nt < 4; ++nt) oacc[nt][j] *= al;
    }
    // P -> bf16 via per-wave LDS (D layout -> A layout transpose)
#pragma unroll
    for (int nt = 0; nt < 4; ++nt)
#pragma unroll
      for (int j = 0; j < 4; ++j)
        plds[w][l4 * 4 + j][nt * 16 + l15] = f2bf(sacc[nt][j]);
    // PV
#pragma unroll
    for (int kb = 0; kb < 2; ++kb) {
      bf16x8 pa = *(const bf16x8*)&plds[w][l15][kb * 32 + l4 * 8];
#pragma unroll
      for (int nt = 0; nt < 4; ++nt) {
        bf16x8 vf = *(const bf16x8*)&vtlds[nt * 16 + l15][kb * 32 + l4 * 8];
        oacc[nt] = __builtin_amdgcn_mfma_f32_16x16x32_bf16(pa, vf, oacc[nt], 0, 0, 0);
      }
    }
  }

  float inv[4];
#pragma unroll
  for (int j = 0; j < 4; ++j) inv[j] = 1.f / lrow[j];
#pragma unroll
  for (int nt = 0; nt < 4; ++nt)
#pragma unroll
    for (int j = 0; j < 4; ++j) {
      int q = q0 + l4 * 4 + j;
      ao[(long)(b * SS + q) * 1024 + h * 64 + nt * 16 + l15] = f2bf(oacc[nt][j] * inv[j]);
    }
}

// ---------------------------------------------------------------- output GEMM
// C(8192x1024) = ao @ Wo^T + bo.  B[k][n] = Wo[n][k] -> stage wob rows as [n][k].
__global__ __launch_bounds__(256) void out_gemm(
    const short* __restrict__ ao, const short* __restrict__ wob,
    const float* __restrict__ bo, float* __restrict__ out)
{
  __shared__ short alds[128][72];
  __shared__ short blds[128][72];
  const int t = threadIdx.x, lane = t & 63, w = t >> 6;
  const int l15 = lane & 15, l4 = lane >> 4;
  const int wm = w >> 1, wn = w & 1;
  const long m0 = (long)blockIdx.y * 128;
  const int n0 = blockIdx.x * 128;

  f32x4 acc[4][4];
#pragma unroll
  for (int mi = 0; mi < 4; ++mi)
#pragma unroll
    for (int ni = 0; ni < 4; ++ni) acc[mi][ni] = (f32x4){0.f, 0.f, 0.f, 0.f};

  for (int k0 = 0; k0 < 1024; k0 += 64) {
    __syncthreads();
#pragma unroll
    for (int i = 0; i < 4; ++i) {
      int f = t * 8 + i * 2048;                  // 8192 bf16 per tile
      int row = f >> 6, col = f & 63;
      *(bf16x8*)&alds[row][col] = *(const bf16x8*)(ao + (m0 + row) * 1024 + k0 + col);
      *(bf16x8*)&blds[row][col] = *(const bf16x8*)(wob + (long)(n0 + row) * 1024 + k0 + col);
    }
    __syncthreads();
#pragma unroll
    for (int kb = 0; kb < 2; ++kb) {
      bf16x8 af[4], bfr[4];
#pragma unroll
      for (int mi = 0; mi < 4; ++mi)
        af[mi] = *(const bf16x8*)&alds[wm * 64 + mi * 16 + l15][kb * 32 + l4 * 8];
#pragma unroll
      for (int ni = 0; ni < 4; ++ni)
        bfr[ni] = *(const bf16x8*)&blds[wn * 64 + ni * 16 + l15][kb * 32 + l4 * 8];
#pragma unroll
      for (int mi = 0; mi < 4; ++mi)
#pragma unroll
        for (int ni = 0; ni < 4; ++ni)
          acc[mi][ni] = __builtin_amdgcn_mfma_f32_16x16x32_bf16(af[mi], bfr[ni], acc[mi][ni], 0, 0, 0);
    }
  }
#pragma unroll
  for (int ni = 0; ni < 4; ++ni) {
    float bias = bo[n0 + wn * 64 + ni * 16 + l15];
#pragma unroll
    for (int mi = 0; mi < 4; ++mi)
#pragma unroll
      for (int j = 0; j < 4; ++j)
        out[(m0 + wm * 64 + mi * 16 + l4 * 4 + j) * 1024 + n0 + wn * 64 + ni * 16 + l15] =
            acc[mi][ni][j] + bias;
  }
}

extern "C" void kernel_launch(void* const* d_in, const int* in_sizes, int n_in,
                              void* d_out, int out_size, void* d_ws, size_t ws_size,
                              hipStream_t stream) {
  const float* values = (const float*)d_in[0];
  const float* keys   = (const float*)d_in[1];
  const float* query  = (const float*)d_in[2];
  const int*   mask   = (const int*)d_in[3];
  const float* Wv     = (const float*)d_in[4];
  const float* Wk     = (const float*)d_in[5];
  const float* Wq     = (const float*)d_in[6];
  const float* Wo     = (const float*)d_in[7];
  const float* bo     = (const float*)d_in[8];
  float* out = (float*)d_out;

  const long NTOK = 4L * SS * HH * DD;      // 8388608 elements per tensor
  short* qp  = (short*)d_ws;
  short* kp  = qp + NTOK;
  short* vp  = kp + NTOK;
  short* aot = vp + NTOK;
  short* wob = aot + NTOK;                  // 1024*1024

  hipLaunchKernelGGL(proj_kernel, dim3(1024), dim3(256), 0, stream,
                     query, keys, values, Wq, Wk, Wv, qp, kp, vp);
  hipLaunchKernelGGL(wo_cvt, dim3(1024), dim3(256), 0, stream, Wo, wob);
  hipLaunchKernelGGL(attn_kernel, dim3(32, 64), dim3(256), 0, stream,
                     qp, kp, vp, mask, aot);
  hipLaunchKernelGGL(out_gemm, dim3(8, 64), dim3(256), 0, stream,
                     aot, wob, bo, out);
}

// Round 2
// 181.889 us; speedup vs baseline: 1.7857x; 1.7857x over previous
//
#include <hip/hip_runtime.h>
#include <hip/hip_bf16.h>

// SelfAttention: B=4, S=2048, EMBED=1024, H=16, D=64
// out = ((softmax((Q Wq^T)(K Wk^T)^T / 32) (V Wv^T)) reshaped) Wo^T + bo
//
// Round 2: swapped-QK^T flash attention (S^T = K·Q via mfma 32x32x16) so each
// lane owns one q-row; softmax fully in-register (1 shfl for max, 1 for sum);
// P->bf16 via cvt_pk + shfl_xor(32) exchange; PV computes O^T = V^T · P^T.
// Scale (1/32)*log2(e) folded into projected Q.

#define SS 2048
#define HH 16
#define DD 64

typedef __attribute__((ext_vector_type(8))) short bf16x8;
typedef __attribute__((ext_vector_type(4))) short s16x4;
typedef __attribute__((ext_vector_type(4))) float f32x4;
typedef __attribute__((ext_vector_type(16))) float f32x16;

__device__ __forceinline__ short f2bf(float f) {
  union { float f; unsigned u; } c; c.f = f;
  unsigned r = (c.u + 0x7FFFu + ((c.u >> 16) & 1u)) >> 16;  // RNE
  return (short)r;
}

__device__ __forceinline__ int cvtpk(float lo, float hi) {
  int r;
  asm("v_cvt_pk_bf16_f32 %0, %1, %2" : "=v"(r) : "v"(lo), "v"(hi));
  return r;
}

// ---------------------------------------------------------------- projections
// rows r = (b*S + s)*16 + h are contiguous (64 f32 each). Block = 128 rows.
// Q output is pre-scaled by (1/sqrt(1024))*log2(e) for the log2-domain softmax.
__global__ __launch_bounds__(256) void proj_kernel(
    const float* __restrict__ xq, const float* __restrict__ xk, const float* __restrict__ xv,
    const float* __restrict__ Wq, const float* __restrict__ Wk, const float* __restrict__ Wv,
    short* __restrict__ qp, short* __restrict__ kp, short* __restrict__ vp)
{
  __shared__ short xlds[128][72];
  __shared__ short wlds[3][64][72];
  const int t = threadIdx.x;
  const int lane = t & 63;
  const int w = t >> 6;
  const int l15 = lane & 15, l4 = lane >> 4;

  const float* wsrc[3] = {Wq, Wk, Wv};
#pragma unroll
  for (int z = 0; z < 3; ++z) {
#pragma unroll
    for (int i = 0; i < 4; ++i) {
      int fi = (t + i * 256) * 4;
      int row = fi >> 6, col = fi & 63;
      float4 a = *(const float4*)(wsrc[z] + fi);
      s16x4 sv = { f2bf(a.x), f2bf(a.y), f2bf(a.z), f2bf(a.w) };
      *(s16x4*)&wlds[z][row][col] = sv;
    }
  }

  const long r0 = (long)blockIdx.x * 128;
  const float* xin[3] = {xq, xk, xv};
  short* outp[3] = {qp, kp, vp};
  const float SCQ = 0.03125f * 1.4426950408889634f;

#pragma unroll
  for (int z = 0; z < 3; ++z) {
    __syncthreads();
    const float* src = xin[z] + r0 * 64;
#pragma unroll
    for (int i = 0; i < 8; ++i) {
      int fi = (t + i * 256) * 4;
      int row = fi >> 6, col = fi & 63;
      float4 a = *(const float4*)(src + fi);
      s16x4 sv = { f2bf(a.x), f2bf(a.y), f2bf(a.z), f2bf(a.w) };
      *(s16x4*)&xlds[row][col] = sv;
    }
    __syncthreads();

    bf16x8 af[2][2];
#pragma unroll
    for (int mi = 0; mi < 2; ++mi)
#pragma unroll
      for (int kb = 0; kb < 2; ++kb)
        af[mi][kb] = *(const bf16x8*)&xlds[w * 32 + mi * 16 + l15][kb * 32 + l4 * 8];

    f32x4 acc[2][4];
#pragma unroll
    for (int mi = 0; mi < 2; ++mi)
#pragma unroll
      for (int nt = 0; nt < 4; ++nt)
        acc[mi][nt] = (f32x4){0.f, 0.f, 0.f, 0.f};

#pragma unroll
    for (int nt = 0; nt < 4; ++nt)
#pragma unroll
      for (int kb = 0; kb < 2; ++kb) {
        bf16x8 bfr = *(const bf16x8*)&wlds[z][nt * 16 + l15][kb * 32 + l4 * 8];
#pragma unroll
        for (int mi = 0; mi < 2; ++mi)
          acc[mi][nt] = __builtin_amdgcn_mfma_f32_16x16x32_bf16(af[mi][kb], bfr, acc[mi][nt], 0, 0, 0);
      }

    short* dst = outp[z];
    const float sc = (z == 0) ? SCQ : 1.0f;
#pragma unroll
    for (int mi = 0; mi < 2; ++mi)
#pragma unroll
      for (int nt = 0; nt < 4; ++nt)
#pragma unroll
        for (int j = 0; j < 4; ++j) {
          int r = (int)r0 + w * 32 + mi * 16 + l4 * 4 + j;   // (b*S+s)*16+h
          int e = nt * 16 + l15;
          int h = r & 15, bs = r >> 4;
          int b = bs >> 11, s = bs & 2047;
          dst[(((long)(b * 16 + h) * 2048 + s) << 6) + e] = f2bf(acc[mi][nt][j] * sc);
        }
  }
}

// ---------------------------------------------------------------- Wo -> bf16
__global__ __launch_bounds__(256) void wo_cvt(const float* __restrict__ Wo,
                                              short* __restrict__ wob) {
  long i = ((long)blockIdx.x * 256 + threadIdx.x) * 4;
  float4 a = *(const float4*)(Wo + i);
  s16x4 sv = { f2bf(a.x), f2bf(a.y), f2bf(a.z), f2bf(a.w) };
  *(s16x4*)(wob + i) = sv;
}

// ---------------------------------------------------------------- attention
// grid (S/128 = 16 q-blocks, 64 bh). Block = 4 waves; each wave owns 32 q-rows.
// Swapped QK^T: S^T[kv][q] = mfma32(A=K, B=Q). Lane: q = lane&31, hi = lane>>5.
// S^T reg layout: kv = (r&3) + 8*(r>>2) + 4*hi (+32*kvblk), col q = lane&31.
__global__ __launch_bounds__(256, 3) void attn_kernel(
    const short* __restrict__ qp, const short* __restrict__ kp, const short* __restrict__ vp,
    const int* __restrict__ mask, short* __restrict__ ao)
{
  __shared__ short klds[64][72];       // K tile [kv][d], +8 pad
  __shared__ short vtlds[64][72];      // V tile transposed [d][kv]
  __shared__ int tile_ok[32];
  const int t = threadIdx.x, lane = t & 63, w = t >> 6;
  const int l31 = lane & 31, hi = lane >> 5;
  const int bh = blockIdx.y, b = bh >> 4, h = bh & 15;
  const short* qb  = qp + (long)bh * SS * DD;
  const short* kbp = kp + (long)bh * SS * DD;
  const short* vbp = vp + (long)bh * SS * DD;
  const int* mb = mask + b * SS;

  if (t < 32) tile_ok[t] = 1;
  __syncthreads();
  {
    int ok = 1;
#pragma unroll
    for (int i = 0; i < 8; ++i) ok &= (mb[t * 8 + i] != 0);
    if (!ok) tile_ok[t >> 3] = 0;
  }

  const int q = blockIdx.x * 128 + w * 32 + l31;
  bf16x8 qf[4];
#pragma unroll
  for (int dblk = 0; dblk < 4; ++dblk)
    qf[dblk] = *(const bf16x8*)(qb + (long)q * 64 + dblk * 16 + hi * 8);

  f32x16 oacc[2];
#pragma unroll
  for (int dt = 0; dt < 2; ++dt)
#pragma unroll
    for (int r = 0; r < 16; ++r) oacc[dt][r] = 0.f;
  float m_reg = -1e30f, l_reg = 0.f;

  for (int kt = 0; kt < SS / 64; ++kt) {
    const int k0 = kt * 64;
    __syncthreads();
    // stage K (contiguous 8KB)
#pragma unroll
    for (int i = 0; i < 2; ++i) {
      int f = t * 8 + i * 2048;
      *(bf16x8*)&klds[f >> 6][f & 63] = *(const bf16x8*)(kbp + (long)k0 * 64 + f);
    }
    // stage V transposed
    {
      int kk = t & 63, d0 = (t >> 6) * 16;
      bf16x8 v0 = *(const bf16x8*)(vbp + (long)(k0 + kk) * 64 + d0);
      bf16x8 v1 = *(const bf16x8*)(vbp + (long)(k0 + kk) * 64 + d0 + 8);
#pragma unroll
      for (int j = 0; j < 8; ++j) vtlds[d0 + j][kk] = v0[j];
#pragma unroll
      for (int j = 0; j < 8; ++j) vtlds[d0 + 8 + j][kk] = v1[j];
    }
    __syncthreads();

    // S^T = K . Q  (two 32-kv blocks, chain K=16 over d=64)
    f32x16 sacc[2];
#pragma unroll
    for (int kb = 0; kb < 2; ++kb) {
#pragma unroll
      for (int r = 0; r < 16; ++r) sacc[kb][r] = 0.f;
#pragma unroll
      for (int dblk = 0; dblk < 4; ++dblk) {
        bf16x8 ka = *(const bf16x8*)&klds[kb * 32 + l31][dblk * 16 + hi * 8];
        sacc[kb] = __builtin_amdgcn_mfma_f32_32x32x16_bf16(ka, qf[dblk], sacc[kb], 0, 0, 0);
      }
    }

    if (!tile_ok[kt]) {   // rare slow path: per-element mask (log2 domain)
#pragma unroll
      for (int kb = 0; kb < 2; ++kb)
#pragma unroll
        for (int r = 0; r < 16; ++r) {
          int kv = k0 + kb * 32 + (r & 3) + 8 * (r >> 2) + 4 * hi;
          if (mb[kv] == 0) sacc[kb][r] = -1e30f;
        }
    }

    // tile max (lane holds 32 of 64 kv for its q; partner lane^32 has the rest)
    float mx = sacc[0][0];
#pragma unroll
    for (int r = 1; r < 16; ++r) mx = fmaxf(mx, sacc[0][r]);
#pragma unroll
    for (int r = 0; r < 16; ++r) mx = fmaxf(mx, sacc[1][r]);
    mx = fmaxf(mx, __shfl_xor(mx, 32));

    // defer-max rescale (T13, THR=8 in log2 domain -> P <= 256)
    if (!__all(mx <= m_reg + 8.f)) {
      float mnew = fmaxf(m_reg, mx);
      float al = exp2f(m_reg - mnew);
      l_reg *= al;
#pragma unroll
      for (int dt = 0; dt < 2; ++dt)
#pragma unroll
        for (int r = 0; r < 16; ++r) oacc[dt][r] *= al;
      m_reg = mnew;
    }

    // P = exp2(S - m), row sum
    float sum = 0.f;
#pragma unroll
    for (int kb = 0; kb < 2; ++kb)
#pragma unroll
      for (int r = 0; r < 16; ++r) {
        float p = exp2f(sacc[kb][r] - m_reg);
        sacc[kb][r] = p;
        sum += p;
      }
    sum += __shfl_xor(sum, 32);
    l_reg += sum;

    // P -> bf16 A/B-fragments: cvt_pk pairs + lane^32 exchange.
    // pa[ks] holds P[q][kv = ks*16 + hi*8 + j], j=0..7.
    union PW { int wd[4]; bf16x8 v; } pa[4];
#pragma unroll
    for (int kb = 0; kb < 2; ++kb)
#pragma unroll
      for (int ks = 0; ks < 2; ++ks) {
        const int rb = ks * 8;
        int a0 = cvtpk(sacc[kb][rb + 0], sacc[kb][rb + 1]);
        int b0 = cvtpk(sacc[kb][rb + 4], sacc[kb][rb + 5]);
        int a1 = cvtpk(sacc[kb][rb + 2], sacc[kb][rb + 3]);
        int b1 = cvtpk(sacc[kb][rb + 6], sacc[kb][rb + 7]);
        int sa0 = __shfl_xor(a0, 32);
        int sb0 = __shfl_xor(b0, 32);
        int sa1 = __shfl_xor(a1, 32);
        int sb1 = __shfl_xor(b1, 32);
        pa[kb * 2 + ks].wd[0] = hi ? sb0 : a0;
        pa[kb * 2 + ks].wd[1] = hi ? sb1 : a1;
        pa[kb * 2 + ks].wd[2] = hi ? b0 : sa0;
        pa[kb * 2 + ks].wd[3] = hi ? b1 : sa1;
      }

    // O^T += V^T . P^T   (A = V^T rows d, B = pa, col q)
#pragma unroll
    for (int dt = 0; dt < 2; ++dt)
#pragma unroll
      for (int ks = 0; ks < 4; ++ks) {
        bf16x8 va = *(const bf16x8*)&vtlds[dt * 32 + l31][ks * 16 + hi * 8];
        oacc[dt] = __builtin_amdgcn_mfma_f32_32x32x16_bf16(va, pa[ks].v, oacc[dt], 0, 0, 0);
      }
  }

  // epilogue: lane holds O^T[d][q=l31]; d = dt*32 + 8g + 4hi + j
  float inv = 1.f / l_reg;
#pragma unroll
  for (int dt = 0; dt < 2; ++dt)
#pragma unroll
    for (int g = 0; g < 4; ++g) {
      s16x4 sv;
#pragma unroll
      for (int j = 0; j < 4; ++j) sv[j] = f2bf(oacc[dt][g * 4 + j] * inv);
      int d0 = dt * 32 + g * 8 + hi * 4;
      *(s16x4*)(ao + (long)(b * SS + q) * 1024 + h * 64 + d0) = sv;
    }
}

// ---------------------------------------------------------------- output GEMM
__global__ __launch_bounds__(256) void out_gemm(
    const short* __restrict__ ao, const short* __restrict__ wob,
    const float* __restrict__ bo, float* __restrict__ out)
{
  __shared__ short alds[128][72];
  __shared__ short blds[128][72];
  const int t = threadIdx.x, lane = t & 63, w = t >> 6;
  const int l15 = lane & 15, l4 = lane >> 4;
  const int wm = w >> 1, wn = w & 1;
  const long m0 = (long)blockIdx.y * 128;
  const int n0 = blockIdx.x * 128;

  f32x4 acc[4][4];
#pragma unroll
  for (int mi = 0; mi < 4; ++mi)
#pragma unroll
    for (int ni = 0; ni < 4; ++ni) acc[mi][ni] = (f32x4){0.f, 0.f, 0.f, 0.f};

  for (int k0 = 0; k0 < 1024; k0 += 64) {
    __syncthreads();
#pragma unroll
    for (int i = 0; i < 4; ++i) {
      int f = t * 8 + i * 2048;
      int row = f >> 6, col = f & 63;
      *(bf16x8*)&alds[row][col] = *(const bf16x8*)(ao + (m0 + row) * 1024 + k0 + col);
      *(bf16x8*)&blds[row][col] = *(const bf16x8*)(wob + (long)(n0 + row) * 1024 + k0 + col);
    }
    __syncthreads();
#pragma unroll
    for (int kb = 0; kb < 2; ++kb) {
      bf16x8 af[4], bfr[4];
#pragma unroll
      for (int mi = 0; mi < 4; ++mi)
        af[mi] = *(const bf16x8*)&alds[wm * 64 + mi * 16 + l15][kb * 32 + l4 * 8];
#pragma unroll
      for (int ni = 0; ni < 4; ++ni)
        bfr[ni] = *(const bf16x8*)&blds[wn * 64 + ni * 16 + l15][kb * 32 + l4 * 8];
#pragma unroll
      for (int mi = 0; mi < 4; ++mi)
#pragma unroll
        for (int ni = 0; ni < 4; ++ni)
          acc[mi][ni] = __builtin_amdgcn_mfma_f32_16x16x32_bf16(af[mi], bfr[ni], acc[mi][ni], 0, 0, 0);
    }
  }
#pragma unroll
  for (int ni = 0; ni < 4; ++ni) {
    float bias = bo[n0 + wn * 64 + ni * 16 + l15];
#pragma unroll
    for (int mi = 0; mi < 4; ++mi)
#pragma unroll
      for (int j = 0; j < 4; ++j)
        out[(m0 + wm * 64 + mi * 16 + l4 * 4 + j) * 1024 + n0 + wn * 64 + ni * 16 + l15] =
            acc[mi][ni][j] + bias;
  }
}

extern "C" void kernel_launch(void* const* d_in, const int* in_sizes, int n_in,
                              void* d_out, int out_size, void* d_ws, size_t ws_size,
                              hipStream_t stream) {
  const float* values = (const float*)d_in[0];
  const float* keys   = (const float*)d_in[1];
  const float* query  = (const float*)d_in[2];
  const int*   mask   = (const int*)d_in[3];
  const float* Wv     = (const float*)d_in[4];
  const float* Wk     = (const float*)d_in[5];
  const float* Wq     = (const float*)d_in[6];
  const float* Wo     = (const float*)d_in[7];
  const float* bo     = (const float*)d_in[8];
  float* out = (float*)d_out;

  const long NTOK = 4L * SS * HH * DD;
  short* qp  = (short*)d_ws;
  short* kp  = qp + NTOK;
  short* vp  = kp + NTOK;
  short* aot = vp + NTOK;
  short* wob = aot + NTOK;

  hipLaunchKernelGGL(proj_kernel, dim3(1024), dim3(256), 0, stream,
                     query, keys, values, Wq, Wk, Wv, qp, kp, vp);
  hipLaunchKernelGGL(wo_cvt, dim3(1024), dim3(256), 0, stream, Wo, wob);
  hipLaunchKernelGGL(attn_kernel, dim3(16, 64), dim3(256), 0, stream,
                     qp, kp, vp, mask, aot);
  hipLaunchKernelGGL(out_gemm, dim3(8, 64), dim3(256), 0, stream,
                     aot, wob, bo, out);
}